// Round 10
// baseline (315.336 us; speedup 1.0000x reference)
//
#include <hip/hip_runtime.h>

// HalfEdgeMeshPool: segment-mean over groups.
// feat: [B, C, N] f32, gid: [B, N] i32 in [0,T), out: [B, C, T] f32.
//
// R1/R2: LDS f32 atomics serialize ~3.2 cyc/lane -> 428us floor.
// R3: random 4B global gather = 14.5x line over-fetch -> 1.7ms.
// R5/R6: sort+transpose (820MB, 2 passes) -> 250us.
// R7: fused single-pass, 160KB LDS -> 318us (1 block/CU, serialized phases).
// R8: fused + 80KB LDS (2 blocks/CU) + padded member-table mt[t][8] -> 199us;
//     phase 2 LDS-gather-issue-bound (8 gathers/group vs mean cnt 2).
// R9: PAD 8->4 (covers 94.7% of Poisson(2) groups), heavy tail -> ext table
//     (hid pre-assigned so fill can scatter directly), ultra-rare (cnt>16)
//     -> tiny list. Phase 2: 16B mt per 2 groups + 4 LDS gathers/group.
static constexpr int B = 8;
static constexpr int C = 256;
static constexpr int N = 40000;
static constexpr int T = 20000;
static constexpr int PAD = 4;                  // mt slots per group
static constexpr int EXTS = 12;                // ext slots per heavy group
static constexpr int CAP = PAD + EXTS;         // 16
static constexpr int MAXH = N / (PAD + 1) + 8; // 8008 heavy-group cap per b
static constexpr int UCAP = 4096;              // ultra list cap per b
static constexpr int LDSU = 40448;             // row_bf u16 slots (data + zero pad)

typedef float  f32x4 __attribute__((ext_vector_type(4)));
typedef float  f32x2 __attribute__((ext_vector_type(2)));
typedef ushort u16x4 __attribute__((ext_vector_type(4)));
typedef ushort u16x8 __attribute__((ext_vector_type(8)));

__device__ __forceinline__ ushort f2bf(float v) {
    unsigned u = __float_as_uint(v);
    u += 0x7FFFu + ((u >> 16) & 1u);  // round-to-nearest-even
    return (ushort)(u >> 16);
}
__device__ __forceinline__ float bf2f(ushort u) {
    return __uint_as_float((unsigned)u << 16);
}

// ---- init: counts=head=0, mt=sentinel(40000), hcnt=ucnt=0 ----
__global__ void __launch_bounds__(256) hemp_init_kernel(int* __restrict__ head,
                                                        int* __restrict__ counts,
                                                        unsigned* __restrict__ mt32,
                                                        int* __restrict__ hcnt,
                                                        int* __restrict__ ucnt) {
    const int stride = gridDim.x * 256;
    int i = blockIdx.x * 256 + threadIdx.x;
    for (int k = i; k < B * T * PAD / 2; k += stride) mt32[k] = 0x9C409C40u;
    for (int k = i; k < B * T; k += stride) { head[k] = 0; counts[k] = 0; }
    if (i < B) { hcnt[i] = 0; ucnt[i] = 0; }
}

// ---- count: per-(b,t) member counts ----
__global__ void __launch_bounds__(256) hemp_count_kernel(const int* __restrict__ gid,
                                                         int* __restrict__ counts) {
    int idx = blockIdx.x * 256 + threadIdx.x;
    if (idx >= B * N / 4) return;
    int b = idx / (N / 4);
    int i4 = idx - b * (N / 4);
    int4 g = reinterpret_cast<const int4*>(gid + (size_t)b * N)[i4];
    int* cb = counts + b * T;
    atomicAdd(&cb[g.x], 1);
    atomicAdd(&cb[g.y], 1);
    atomicAdd(&cb[g.z], 1);
    atomicAdd(&cb[g.w], 1);
}

// ---- assign: heavy groups (cnt>PAD) get a compact hid; hg maps hid->t ----
__global__ void __launch_bounds__(256) hemp_assign_kernel(const int* __restrict__ counts,
                                                          int* __restrict__ hidmap,
                                                          int* __restrict__ hg,
                                                          int* __restrict__ hcnt) {
    int i = blockIdx.x * 256 + threadIdx.x;
    if (i >= B * T) return;
    int b = i / T;
    int t = i - b * T;
    if (counts[i] > PAD) {
        int h = atomicAdd(&hcnt[b], 1);
        hidmap[i] = h;
        hg[b * MAXH + h] = t;
    }
}

// ---- fill: rank r -> mt (r<PAD) / ext[hid] (r<CAP) / ultra list ----
__global__ void __launch_bounds__(256) hemp_fill_kernel(const int* __restrict__ gid,
                                                        const int* __restrict__ hidmap,
                                                        int* __restrict__ head,
                                                        ushort* __restrict__ mt,
                                                        ushort* __restrict__ ext,
                                                        unsigned* __restrict__ ultra,
                                                        int* __restrict__ ucnt) {
    int idx = blockIdx.x * 256 + threadIdx.x;
    if (idx >= B * N) return;
    int b = idx / N;
    int n = idx - b * N;
    int g = gid[idx];
    int r = atomicAdd(&head[b * T + g], 1);
    if (r < PAD) {
        mt[((size_t)(b * T + g)) * PAD + r] = (ushort)n;
    } else if (r < CAP) {
        ext[((size_t)b * MAXH + hidmap[b * T + g]) * EXTS + (r - PAD)] = (ushort)n;
    } else {
        int u = atomicAdd(&ucnt[b], 1);
        if (u < UCAP) ultra[b * UCAP + u] = ((unsigned)g << 16) | (unsigned)n;
    }
}

// ---- fused: one block per (b,c). Stream row->LDS bf16; 4 gathers per group ----
__global__ void __launch_bounds__(512) hemp_fused_kernel(const float* __restrict__ feat,
                                                         const ushort* __restrict__ mt,
                                                         const ushort* __restrict__ ext,
                                                         const int* __restrict__ counts,
                                                         const int* __restrict__ hg,
                                                         const int* __restrict__ hcnt,
                                                         const unsigned* __restrict__ ultra,
                                                         const int* __restrict__ ucnt,
                                                         float* __restrict__ out) {
    extern __shared__ ushort row_bf[];  // LDSU u16 = 80896 B -> 2 blocks/CU
    const int tid = threadIdx.x;
    const int b = blockIdx.x >> 8;  // same-b blocks adjacent -> mt/counts L2-hot
    const int c = blockIdx.x & 255;

    // zero the pad region (sentinel 40000 lands here)
    if (tid < (LDSU - N) / 4)
        *reinterpret_cast<u16x4*>(&row_bf[N + tid * 4]) = (u16x4){0, 0, 0, 0};

    // Phase 1: stream feature row into LDS as bf16 (unroll-2 for load depth)
    const f32x4* __restrict__ f4 =
        reinterpret_cast<const f32x4*>(feat + (size_t)(b * C + c) * N);
    for (int i = tid; i < N / 4; i += 1024) {
        f32x4 v0 = __builtin_nontemporal_load(f4 + i);
        const int i2 = i + 512;
        const bool ok = i2 < N / 4;
        f32x4 v1 = {};
        if (ok) v1 = __builtin_nontemporal_load(f4 + i2);
        u16x4 w0 = {f2bf(v0.x), f2bf(v0.y), f2bf(v0.z), f2bf(v0.w)};
        *reinterpret_cast<u16x4*>(&row_bf[i * 4]) = w0;
        if (ok) {
            u16x4 w1 = {f2bf(v1.x), f2bf(v1.y), f2bf(v1.z), f2bf(v1.w)};
            *reinterpret_cast<u16x4*>(&row_bf[i2 * 4]) = w1;
        }
    }
    __syncthreads();

    // Phase 2: 2 groups/thread/iter: 16B mt load, 8B counts, 4 gathers/group,
    // coalesced f32x2 store.
    const ushort* __restrict__ mtb = mt + (size_t)b * T * PAD;
    const int* __restrict__ cntb = counts + b * T;
    float* __restrict__ orow = out + (size_t)(b * C + c) * T;
    for (int t2 = tid * 2; t2 < T; t2 += 1024) {
        u16x8 m = *reinterpret_cast<const u16x8*>(mtb + (size_t)t2 * PAD);
        int2 cn = *reinterpret_cast<const int2*>(cntb + t2);
        float s0 = (bf2f(row_bf[m[0]]) + bf2f(row_bf[m[1]])) +
                   (bf2f(row_bf[m[2]]) + bf2f(row_bf[m[3]]));
        float s1 = (bf2f(row_bf[m[4]]) + bf2f(row_bf[m[5]])) +
                   (bf2f(row_bf[m[6]]) + bf2f(row_bf[m[7]]));
        if (cn.x <= PAD && cn.y <= PAD) {
            f32x2 r = {s0 / fmaxf((float)cn.x, 1.0f), s1 / fmaxf((float)cn.y, 1.0f)};
            __builtin_nontemporal_store(r, reinterpret_cast<f32x2*>(orow + t2));
        } else {
            if (cn.x <= PAD)
                __builtin_nontemporal_store(s0 / fmaxf((float)cn.x, 1.0f), orow + t2);
            if (cn.y <= PAD)
                __builtin_nontemporal_store(s1 / fmaxf((float)cn.y, 1.0f), orow + t2 + 1);
        }
    }

    // Epilogue: heavy groups (cnt>PAD): 4 mt + (cnt-4) ext gathers; ultra scan.
    const int H = hcnt[b];
    const ushort* __restrict__ extb = ext + (size_t)b * MAXH * EXTS;
    for (int i = tid; i < H; i += 512) {
        const int g = hg[b * MAXH + i];
        const int cnt = cntb[g];
        const ushort* mg = mtb + (size_t)g * PAD;
        float s = (bf2f(row_bf[mg[0]]) + bf2f(row_bf[mg[1]])) +
                  (bf2f(row_bf[mg[2]]) + bf2f(row_bf[mg[3]]));
        const ushort* eg = extb + (size_t)i * EXTS;
        const int e = min(cnt, CAP) - PAD;
        for (int k = 0; k < e; ++k) s += bf2f(row_bf[eg[k]]);
        if (cnt > CAP) {
            const int U = min(ucnt[b], UCAP);
            const unsigned* ub = ultra + b * UCAP;
            for (int u = 0; u < U; ++u) {
                unsigned w = ub[u];
                if ((w >> 16) == (unsigned)g) s += bf2f(row_bf[w & 0xFFFFu]);
            }
        }
        orow[g] = s / (float)cnt;
    }
}

// ---- fallback (ws too small): R2 LDS-atomic kernel ----
static constexpr int BLK = 1024;
__global__ void __launch_bounds__(256) hemp_zero_kernel(int* __restrict__ counts) {
    int i = blockIdx.x * 256 + threadIdx.x;
    if (i < B * T) counts[i] = 0;
}
__global__ void __launch_bounds__(256) hemp_count1_kernel(const int* __restrict__ gid,
                                                          int* __restrict__ counts) {
    int idx = blockIdx.x * 256 + threadIdx.x;
    if (idx < B * N) {
        int b = idx / N;
        atomicAdd(&counts[b * T + gid[idx]], 1);
    }
}
__global__ void __launch_bounds__(BLK) hemp_atomic_kernel(const float* __restrict__ feat,
                                                          const int* __restrict__ gid,
                                                          const int* __restrict__ counts,
                                                          float* __restrict__ out) {
    extern __shared__ float lds_sum[];
    const int tid = threadIdx.x;
    const int b = blockIdx.x >> 8;
    const int c = blockIdx.x & 255;
    float4* ls4 = reinterpret_cast<float4*>(lds_sum);
    for (int t = tid; t < T / 4; t += BLK) ls4[t] = make_float4(0.f, 0.f, 0.f, 0.f);
    __syncthreads();
    const float4* f4 = reinterpret_cast<const float4*>(feat + (size_t)(b * C + c) * N);
    const int4* g4 = reinterpret_cast<const int4*>(gid + (size_t)b * N);
    for (int i = tid; i < N / 4; i += BLK) {
        float4 v = f4[i];
        int4 g = g4[i];
        unsafeAtomicAdd(&lds_sum[g.x], v.x);
        unsafeAtomicAdd(&lds_sum[g.y], v.y);
        unsafeAtomicAdd(&lds_sum[g.z], v.z);
        unsafeAtomicAdd(&lds_sum[g.w], v.w);
    }
    __syncthreads();
    const int4* cnt4 = reinterpret_cast<const int4*>(counts + (size_t)b * T);
    float4* out4 = reinterpret_cast<float4*>(out + (size_t)(b * C + c) * T);
    for (int t = tid; t < T / 4; t += BLK) {
        int4 cn = cnt4[t];
        float4 s = ls4[t];
        float4 r;
        r.x = s.x / fmaxf((float)cn.x, 1.0f);
        r.y = s.y / fmaxf((float)cn.y, 1.0f);
        r.z = s.z / fmaxf((float)cn.z, 1.0f);
        r.w = s.w / fmaxf((float)cn.w, 1.0f);
        out4[t] = r;
    }
}

extern "C" void kernel_launch(void* const* d_in, const int* in_sizes, int n_in,
                              void* d_out, int out_size, void* d_ws, size_t ws_size,
                              hipStream_t stream) {
    const float* feat = (const float*)d_in[0];
    const int* gid = (const int*)d_in[1];
    float* out = (float*)d_out;

    // ws: head|counts|hidmap [B*T] i32, mt[B*T*PAD] u16, ext[B*MAXH*EXTS] u16,
    //     hg[B*MAXH] i32, ultra[B*UCAP] u32, hcnt[B], ucnt[B]   (~5.2 MB)
    char* p = (char*)d_ws;
    int* head = (int*)p;         p += (size_t)B * T * 4;
    int* counts = (int*)p;       p += (size_t)B * T * 4;
    int* hidmap = (int*)p;       p += (size_t)B * T * 4;
    ushort* mt = (ushort*)p;     p += (size_t)B * T * PAD * 2;
    ushort* ext = (ushort*)p;    p += (size_t)B * MAXH * EXTS * 2;
    int* hg = (int*)p;           p += (size_t)B * MAXH * 4;
    unsigned* ultra = (unsigned*)p; p += (size_t)B * UCAP * 4;
    int* hcnt = (int*)p;         p += (size_t)B * 4;
    int* ucnt = (int*)p;         p += (size_t)B * 4;
    size_t need = (size_t)(p - (char*)d_ws);

    if (ws_size >= need) {
        hemp_init_kernel<<<1280, 256, 0, stream>>>(head, counts, (unsigned*)mt, hcnt, ucnt);
        hemp_count_kernel<<<(B * N / 4 + 255) / 256, 256, 0, stream>>>(gid, counts);
        hemp_assign_kernel<<<(B * T + 255) / 256, 256, 0, stream>>>(counts, hidmap, hg, hcnt);
        hemp_fill_kernel<<<(B * N + 255) / 256, 256, 0, stream>>>(gid, hidmap, head, mt,
                                                                  ext, ultra, ucnt);
        const int lds_bytes = LDSU * 2;  // 80896 B -> 2 blocks/CU
        hipFuncSetAttribute(reinterpret_cast<const void*>(hemp_fused_kernel),
                            hipFuncAttributeMaxDynamicSharedMemorySize, lds_bytes);
        hemp_fused_kernel<<<B * C, 512, lds_bytes, stream>>>(feat, mt, ext, counts, hg,
                                                             hcnt, ultra, ucnt, out);
    } else {
        int* cnts = (int*)d_ws;
        hemp_zero_kernel<<<(B * T + 255) / 256, 256, 0, stream>>>(cnts);
        hemp_count1_kernel<<<(B * N + 255) / 256, 256, 0, stream>>>(gid, cnts);
        const size_t lds_bytes = (size_t)T * sizeof(float);
        hipFuncSetAttribute(reinterpret_cast<const void*>(hemp_atomic_kernel),
                            hipFuncAttributeMaxDynamicSharedMemorySize, (int)lds_bytes);
        hemp_atomic_kernel<<<B * C, BLK, lds_bytes, stream>>>(feat, gid, cnts, out);
    }
}

// Round 11
// 142.018 us; speedup vs baseline: 2.2204x; 2.2204x over previous
//
#include <hip/hip_runtime.h>

// HalfEdgeMeshPool: segment-mean over groups.
// feat: [B, C, N] f32, gid: [B, N] i32 in [0,T), out: [B, C, T] f32.
//
// R1/R2: LDS f32 atomics serialize ~3.2 cyc/lane -> 428us floor.
// R3: random 4B global gather = 14.5x line over-fetch -> 1.7ms.
// R5/R6: sort+transpose (820MB, 2 passes) -> 250us.
// R7: fused single-pass, 160KB LDS -> 318us (1 block/CU, serialized phases).
// R8: fused, 80KB LDS, mt[t][8] member table -> 199us (fused ~165, latency-bound).
// R9/R10: PAD=4 + ext/assign -> 315us REGRESSION: epilogue's scattered 4B writes
//         amplified WRITE 160->259MB; prepass ballooned. Tails must stay tiny.
// R11: back to R8 structure; concurrency fix: 1024-thr blocks (2/CU = 2048 thr
//      = HW max, 32 waves/CU), no NT on loads (keep L3 serving feat), NT stores
//      only, unroll-2 ILP in phase 2.
static constexpr int B = 8;
static constexpr int C = 256;
static constexpr int N = 40000;
static constexpr int T = 20000;
static constexpr int PAD = 8;                  // mt slots per group (P(cnt>8)~1e-3)
static constexpr int MAXH = N / (PAD + 1) + 8; // heavy-group cap per b
static constexpr int LDSU = 40448;             // row_bf u16 slots (data + zero pad)
static constexpr int FTH = 1024;               // fused block threads

typedef float  f32x4 __attribute__((ext_vector_type(4)));
typedef ushort u16x4 __attribute__((ext_vector_type(4)));
typedef ushort u16x8 __attribute__((ext_vector_type(8)));

__device__ __forceinline__ ushort f2bf(float v) {
    unsigned u = __float_as_uint(v);
    u += 0x7FFFu + ((u >> 16) & 1u);  // round-to-nearest-even
    return (ushort)(u >> 16);
}
__device__ __forceinline__ float bf2f(ushort u) {
    return __uint_as_float((unsigned)u << 16);
}

// ---- init: head=0, mt=sentinel(40000=0x9C40), hcnt=ocnt=0 ----
__global__ void __launch_bounds__(256) hemp_init_kernel(int* __restrict__ head,
                                                        unsigned* __restrict__ mt32,
                                                        int* __restrict__ hcnt,
                                                        int* __restrict__ ocnt) {
    const int stride = gridDim.x * 256;
    int i = blockIdx.x * 256 + threadIdx.x;
    for (int k = i; k < B * T * PAD / 2; k += stride) mt32[k] = 0x9C409C40u;
    for (int k = i; k < B * T; k += stride) head[k] = 0;
    if (i < B) { hcnt[i] = 0; ocnt[i] = 0; }
}

// ---- fill: rank within group -> mt slot; count>PAD members -> overflow list ----
__global__ void __launch_bounds__(256) hemp_fill_kernel(const int* __restrict__ gid,
                                                        int* __restrict__ head,
                                                        ushort* __restrict__ mt,
                                                        unsigned* __restrict__ of,
                                                        int* __restrict__ hg,
                                                        int* __restrict__ hcnt,
                                                        int* __restrict__ ocnt) {
    int idx = blockIdx.x * 256 + threadIdx.x;
    if (idx >= B * N) return;
    int b = idx / N;
    int n = idx - b * N;
    int g = gid[idx];
    int r = atomicAdd(&head[b * T + g], 1);  // head ends as per-group count
    if (r < PAD) {
        mt[((size_t)(b * T + g)) * PAD + r] = (ushort)n;
    } else {
        int o = atomicAdd(&ocnt[b], 1);
        of[(size_t)b * N + o] = ((unsigned)g << 16) | (unsigned)n;
        if (r == PAD) {  // first overflow: register g as heavy
            int h = atomicAdd(&hcnt[b], 1);
            hg[b * MAXH + h] = g;
        }
    }
}

// ---- fused: one block per (b,c). Stream row->LDS bf16; 8-gather per group ----
__global__ void __launch_bounds__(FTH) hemp_fused_kernel(const float* __restrict__ feat,
                                                         const ushort* __restrict__ mt,
                                                         const int* __restrict__ head,
                                                         const unsigned* __restrict__ of,
                                                         const int* __restrict__ hg,
                                                         const int* __restrict__ hcnt,
                                                         const int* __restrict__ ocnt,
                                                         float* __restrict__ out) {
    extern __shared__ ushort row_bf[];  // LDSU u16 = 80896 B -> 2 blocks/CU
    const int tid = threadIdx.x;
    const int b = blockIdx.x >> 8;  // same-b blocks adjacent -> mt/counts L2-hot
    const int c = blockIdx.x & 255;

    // zero the pad region (sentinel 40000 lands here)
    if (tid < (LDSU - N) / 4)
        *reinterpret_cast<u16x4*>(&row_bf[N + tid * 4]) = (u16x4){0, 0, 0, 0};

    // Phase 1: stream feature row into LDS as bf16 (unroll-2 for load depth)
    const f32x4* __restrict__ f4 =
        reinterpret_cast<const f32x4*>(feat + (size_t)(b * C + c) * N);
    for (int i = tid; i < N / 4; i += 2 * FTH) {
        f32x4 v0 = f4[i];
        const int i2 = i + FTH;
        const bool ok = i2 < N / 4;
        f32x4 v1 = {};
        if (ok) v1 = f4[i2];
        u16x4 w0 = {f2bf(v0.x), f2bf(v0.y), f2bf(v0.z), f2bf(v0.w)};
        *reinterpret_cast<u16x4*>(&row_bf[i * 4]) = w0;
        if (ok) {
            u16x4 w1 = {f2bf(v1.x), f2bf(v1.y), f2bf(v1.z), f2bf(v1.w)};
            *reinterpret_cast<u16x4*>(&row_bf[i2 * 4]) = w1;
        }
    }
    __syncthreads();

    // Phase 2: unroll-2 (two independent chains in flight): per group one 16B
    // coalesced mt load + 4B cnt + 8 LDS gathers + 4B coalesced store.
    const ushort* __restrict__ mtb = mt + (size_t)b * T * PAD;
    const int* __restrict__ cntb = head + b * T;
    float* __restrict__ orow = out + (size_t)(b * C + c) * T;
    for (int t = tid; t < T; t += 2 * FTH) {
        const int t1 = t + FTH;
        const bool ok = t1 < T;
        u16x8 m0 = *reinterpret_cast<const u16x8*>(mtb + (size_t)t * PAD);
        u16x8 m1 = {};
        if (ok) m1 = *reinterpret_cast<const u16x8*>(mtb + (size_t)t1 * PAD);
        int cn0 = cntb[t];
        int cn1 = ok ? cntb[t1] : 0;
        float s0 = ((bf2f(row_bf[m0[0]]) + bf2f(row_bf[m0[1]])) +
                    (bf2f(row_bf[m0[2]]) + bf2f(row_bf[m0[3]]))) +
                   ((bf2f(row_bf[m0[4]]) + bf2f(row_bf[m0[5]])) +
                    (bf2f(row_bf[m0[6]]) + bf2f(row_bf[m0[7]])));
        if (cn0 <= PAD)
            __builtin_nontemporal_store(s0 / fmaxf((float)cn0, 1.0f), orow + t);
        if (ok) {
            float s1 = ((bf2f(row_bf[m1[0]]) + bf2f(row_bf[m1[1]])) +
                        (bf2f(row_bf[m1[2]]) + bf2f(row_bf[m1[3]]))) +
                       ((bf2f(row_bf[m1[4]]) + bf2f(row_bf[m1[5]])) +
                        (bf2f(row_bf[m1[6]]) + bf2f(row_bf[m1[7]])));
            if (cn1 <= PAD)
                __builtin_nontemporal_store(s1 / fmaxf((float)cn1, 1.0f), orow + t1);
        }
    }

    // Epilogue: heavy groups (count>PAD, ~22 per mesh) — mt + overflow scan
    const int H = hcnt[b];
    if (H > 0) {
        const int O = ocnt[b];
        const unsigned* __restrict__ ofb = of + (size_t)b * N;
        for (int i = tid; i < H; i += FTH) {
            const int g = hg[b * MAXH + i];
            const ushort* mg = mtb + (size_t)g * PAD;
            float s = 0.0f;
            #pragma unroll
            for (int k = 0; k < PAD; ++k) s += bf2f(row_bf[mg[k]]);
            for (int e = 0; e < O; ++e) {
                unsigned w = ofb[e];
                if ((w >> 16) == (unsigned)g) s += bf2f(row_bf[w & 0xFFFFu]);
            }
            orow[g] = s / (float)cntb[g];
        }
    }
}

// ---- fallback (ws too small): R2 LDS-atomic kernel ----
static constexpr int BLK = 1024;
__global__ void __launch_bounds__(256) hemp_zero_kernel(int* __restrict__ counts) {
    int i = blockIdx.x * 256 + threadIdx.x;
    if (i < B * T) counts[i] = 0;
}
__global__ void __launch_bounds__(256) hemp_count1_kernel(const int* __restrict__ gid,
                                                          int* __restrict__ counts) {
    int idx = blockIdx.x * 256 + threadIdx.x;
    if (idx < B * N) {
        int b = idx / N;
        atomicAdd(&counts[b * T + gid[idx]], 1);
    }
}
__global__ void __launch_bounds__(BLK) hemp_atomic_kernel(const float* __restrict__ feat,
                                                          const int* __restrict__ gid,
                                                          const int* __restrict__ counts,
                                                          float* __restrict__ out) {
    extern __shared__ float lds_sum[];
    const int tid = threadIdx.x;
    const int b = blockIdx.x >> 8;
    const int c = blockIdx.x & 255;
    float4* ls4 = reinterpret_cast<float4*>(lds_sum);
    for (int t = tid; t < T / 4; t += BLK) ls4[t] = make_float4(0.f, 0.f, 0.f, 0.f);
    __syncthreads();
    const float4* f4 = reinterpret_cast<const float4*>(feat + (size_t)(b * C + c) * N);
    const int4* g4 = reinterpret_cast<const int4*>(gid + (size_t)b * N);
    for (int i = tid; i < N / 4; i += BLK) {
        float4 v = f4[i];
        int4 g = g4[i];
        unsafeAtomicAdd(&lds_sum[g.x], v.x);
        unsafeAtomicAdd(&lds_sum[g.y], v.y);
        unsafeAtomicAdd(&lds_sum[g.z], v.z);
        unsafeAtomicAdd(&lds_sum[g.w], v.w);
    }
    __syncthreads();
    const int4* cnt4 = reinterpret_cast<const int4*>(counts + (size_t)b * T);
    float4* out4 = reinterpret_cast<float4*>(out + (size_t)(b * C + c) * T);
    for (int t = tid; t < T / 4; t += BLK) {
        int4 cn = cnt4[t];
        float4 s = ls4[t];
        float4 r;
        r.x = s.x / fmaxf((float)cn.x, 1.0f);
        r.y = s.y / fmaxf((float)cn.y, 1.0f);
        r.z = s.z / fmaxf((float)cn.z, 1.0f);
        r.w = s.w / fmaxf((float)cn.w, 1.0f);
        out4[t] = r;
    }
}

extern "C" void kernel_launch(void* const* d_in, const int* in_sizes, int n_in,
                              void* d_out, int out_size, void* d_ws, size_t ws_size,
                              hipStream_t stream) {
    const float* feat = (const float*)d_in[0];
    const int* gid = (const int*)d_in[1];
    float* out = (float*)d_out;

    // ws: head[B*T] i32 | mt[B*T*PAD] u16 | of[B*N] u32 | hg[B*MAXH] i32 | hcnt[B] | ocnt[B]
    char* p = (char*)d_ws;
    int* head = (int*)p;            p += (size_t)B * T * 4;
    ushort* mt = (ushort*)p;        p += (size_t)B * T * PAD * 2;
    unsigned* of = (unsigned*)p;    p += (size_t)B * N * 4;
    int* hg = (int*)p;              p += (size_t)B * MAXH * 4;
    int* hcnt = (int*)p;            p += (size_t)B * 4;
    int* ocnt = (int*)p;            p += (size_t)B * 4;
    size_t need = (size_t)(p - (char*)d_ws);

    if (ws_size >= need) {
        hemp_init_kernel<<<2560, 256, 0, stream>>>(head, (unsigned*)mt, hcnt, ocnt);
        hemp_fill_kernel<<<(B * N + 255) / 256, 256, 0, stream>>>(gid, head, mt, of,
                                                                  hg, hcnt, ocnt);
        const int lds_bytes = LDSU * 2;  // 80896 B -> 2 blocks/CU
        hipFuncSetAttribute(reinterpret_cast<const void*>(hemp_fused_kernel),
                            hipFuncAttributeMaxDynamicSharedMemorySize, lds_bytes);
        hemp_fused_kernel<<<B * C, FTH, lds_bytes, stream>>>(feat, mt, head, of, hg,
                                                             hcnt, ocnt, out);
    } else {
        int* cnts = (int*)d_ws;
        hemp_zero_kernel<<<(B * T + 255) / 256, 256, 0, stream>>>(cnts);
        hemp_count1_kernel<<<(B * N + 255) / 256, 256, 0, stream>>>(gid, cnts);
        const size_t lds_bytes = (size_t)T * sizeof(float);
        hipFuncSetAttribute(reinterpret_cast<const void*>(hemp_atomic_kernel),
                            hipFuncAttributeMaxDynamicSharedMemorySize, (int)lds_bytes);
        hemp_atomic_kernel<<<B * C, BLK, lds_bytes, stream>>>(feat, gid, cnts, out);
    }
}

// Round 12
// 140.431 us; speedup vs baseline: 2.2455x; 1.0113x over previous
//
#include <hip/hip_runtime.h>

// HalfEdgeMeshPool: segment-mean over groups.
// feat: [B, C, N] f32, gid: [B, N] i32 in [0,T), out: [B, C, T] f32.
//
// R1/R2: LDS f32 atomics serialize ~3.2 cyc/lane -> 428us floor.
// R3: random 4B global gather = 14.5x line over-fetch -> 1.7ms.
// R5/R6: sort+transpose (820MB, 2 passes) -> 250us.
// R7: fused single-pass, 160KB LDS -> 318us (1 block/CU, serialized phases).
// R8: fused, 80KB LDS, mt[t][8] member table -> 199us.
// R9/R10: PAD=4 + ext tables -> 315us REGRESSION (scattered-write amplification).
// R11: R8 + 1024-thr blocks (2048 thr/CU = HW max) -> 142us.
// R12: prepass trim (int4-vectorized fill) + rcp instead of divide in phase 2.
static constexpr int B = 8;
static constexpr int C = 256;
static constexpr int N = 40000;
static constexpr int T = 20000;
static constexpr int PAD = 8;                  // mt slots per group (P(cnt>8)~1e-3)
static constexpr int MAXH = N / (PAD + 1) + 8; // heavy-group cap per b
static constexpr int LDSU = 40448;             // row_bf u16 slots (data + zero pad)
static constexpr int FTH = 1024;               // fused block threads

typedef float  f32x4 __attribute__((ext_vector_type(4)));
typedef ushort u16x4 __attribute__((ext_vector_type(4)));
typedef ushort u16x8 __attribute__((ext_vector_type(8)));

__device__ __forceinline__ ushort f2bf(float v) {
    unsigned u = __float_as_uint(v);
    u += 0x7FFFu + ((u >> 16) & 1u);  // round-to-nearest-even
    return (ushort)(u >> 16);
}
__device__ __forceinline__ float bf2f(ushort u) {
    return __uint_as_float((unsigned)u << 16);
}

// ---- init: head=0, mt=sentinel(40000=0x9C40), hcnt=ocnt=0 ----
__global__ void __launch_bounds__(256) hemp_init_kernel(int* __restrict__ head,
                                                        unsigned* __restrict__ mt32,
                                                        int* __restrict__ hcnt,
                                                        int* __restrict__ ocnt) {
    const int stride = gridDim.x * 256;
    int i = blockIdx.x * 256 + threadIdx.x;
    for (int k = i; k < B * T * PAD / 2; k += stride) mt32[k] = 0x9C409C40u;
    for (int k = i; k < B * T; k += stride) head[k] = 0;
    if (i < B) { hcnt[i] = 0; ocnt[i] = 0; }
}

// ---- fill (int4): rank within group -> mt slot; overflow -> list ----
__global__ void __launch_bounds__(256) hemp_fill_kernel(const int* __restrict__ gid,
                                                        int* __restrict__ head,
                                                        ushort* __restrict__ mt,
                                                        unsigned* __restrict__ of,
                                                        int* __restrict__ hg,
                                                        int* __restrict__ hcnt,
                                                        int* __restrict__ ocnt) {
    int idx = blockIdx.x * 256 + threadIdx.x;
    if (idx >= B * N / 4) return;
    const int b = idx / (N / 4);
    const int i4 = idx - b * (N / 4);
    const int4 g = reinterpret_cast<const int4*>(gid + (size_t)b * N)[i4];
    int* hb = head + b * T;
    const int n = i4 * 4;
    #pragma unroll
    for (int k = 0; k < 4; ++k) {
        const int gg = (k == 0) ? g.x : (k == 1) ? g.y : (k == 2) ? g.z : g.w;
        const int r = atomicAdd(&hb[gg], 1);  // head ends as per-group count
        if (r < PAD) {
            mt[((size_t)(b * T + gg)) * PAD + r] = (ushort)(n + k);
        } else {
            int o = atomicAdd(&ocnt[b], 1);
            of[(size_t)b * N + o] = ((unsigned)gg << 16) | (unsigned)(n + k);
            if (r == PAD) {  // first overflow: register gg as heavy
                int h = atomicAdd(&hcnt[b], 1);
                hg[b * MAXH + h] = gg;
            }
        }
    }
}

// ---- fused: one block per (b,c). Stream row->LDS bf16; 8-gather per group ----
__global__ void __launch_bounds__(FTH) hemp_fused_kernel(const float* __restrict__ feat,
                                                         const ushort* __restrict__ mt,
                                                         const int* __restrict__ head,
                                                         const unsigned* __restrict__ of,
                                                         const int* __restrict__ hg,
                                                         const int* __restrict__ hcnt,
                                                         const int* __restrict__ ocnt,
                                                         float* __restrict__ out) {
    extern __shared__ ushort row_bf[];  // LDSU u16 = 80896 B -> 2 blocks/CU
    const int tid = threadIdx.x;
    const int b = blockIdx.x >> 8;  // same-b blocks adjacent -> mt/counts L2-hot
    const int c = blockIdx.x & 255;

    // zero the pad region (sentinel 40000 lands here)
    if (tid < (LDSU - N) / 4)
        *reinterpret_cast<u16x4*>(&row_bf[N + tid * 4]) = (u16x4){0, 0, 0, 0};

    // Phase 1: stream feature row into LDS as bf16 (unroll-2 for load depth)
    const f32x4* __restrict__ f4 =
        reinterpret_cast<const f32x4*>(feat + (size_t)(b * C + c) * N);
    for (int i = tid; i < N / 4; i += 2 * FTH) {
        f32x4 v0 = f4[i];
        const int i2 = i + FTH;
        const bool ok = i2 < N / 4;
        f32x4 v1 = {};
        if (ok) v1 = f4[i2];
        u16x4 w0 = {f2bf(v0.x), f2bf(v0.y), f2bf(v0.z), f2bf(v0.w)};
        *reinterpret_cast<u16x4*>(&row_bf[i * 4]) = w0;
        if (ok) {
            u16x4 w1 = {f2bf(v1.x), f2bf(v1.y), f2bf(v1.z), f2bf(v1.w)};
            *reinterpret_cast<u16x4*>(&row_bf[i2 * 4]) = w1;
        }
    }
    __syncthreads();

    // Phase 2: unroll-2 (two independent chains): per group one 16B coalesced
    // mt load + 4B cnt + 8 LDS gathers + rcp-scaled 4B coalesced NT store.
    const ushort* __restrict__ mtb = mt + (size_t)b * T * PAD;
    const int* __restrict__ cntb = head + b * T;
    float* __restrict__ orow = out + (size_t)(b * C + c) * T;
    for (int t = tid; t < T; t += 2 * FTH) {
        const int t1 = t + FTH;
        const bool ok = t1 < T;
        u16x8 m0 = *reinterpret_cast<const u16x8*>(mtb + (size_t)t * PAD);
        u16x8 m1 = {};
        if (ok) m1 = *reinterpret_cast<const u16x8*>(mtb + (size_t)t1 * PAD);
        int cn0 = cntb[t];
        int cn1 = ok ? cntb[t1] : 0;
        float s0 = ((bf2f(row_bf[m0[0]]) + bf2f(row_bf[m0[1]])) +
                    (bf2f(row_bf[m0[2]]) + bf2f(row_bf[m0[3]]))) +
                   ((bf2f(row_bf[m0[4]]) + bf2f(row_bf[m0[5]])) +
                    (bf2f(row_bf[m0[6]]) + bf2f(row_bf[m0[7]])));
        if (cn0 <= PAD)
            __builtin_nontemporal_store(
                s0 * __builtin_amdgcn_rcpf(fmaxf((float)cn0, 1.0f)), orow + t);
        if (ok) {
            float s1 = ((bf2f(row_bf[m1[0]]) + bf2f(row_bf[m1[1]])) +
                        (bf2f(row_bf[m1[2]]) + bf2f(row_bf[m1[3]]))) +
                       ((bf2f(row_bf[m1[4]]) + bf2f(row_bf[m1[5]])) +
                        (bf2f(row_bf[m1[6]]) + bf2f(row_bf[m1[7]])));
            if (cn1 <= PAD)
                __builtin_nontemporal_store(
                    s1 * __builtin_amdgcn_rcpf(fmaxf((float)cn1, 1.0f)), orow + t1);
        }
    }

    // Epilogue: heavy groups (count>PAD, ~22 per mesh) — mt + overflow scan
    const int H = hcnt[b];
    if (H > 0) {
        const int O = ocnt[b];
        const unsigned* __restrict__ ofb = of + (size_t)b * N;
        for (int i = tid; i < H; i += FTH) {
            const int g = hg[b * MAXH + i];
            const ushort* mg = mtb + (size_t)g * PAD;
            float s = 0.0f;
            #pragma unroll
            for (int k = 0; k < PAD; ++k) s += bf2f(row_bf[mg[k]]);
            for (int e = 0; e < O; ++e) {
                unsigned w = ofb[e];
                if ((w >> 16) == (unsigned)g) s += bf2f(row_bf[w & 0xFFFFu]);
            }
            orow[g] = s / (float)cntb[g];
        }
    }
}

// ---- fallback (ws too small): R2 LDS-atomic kernel ----
static constexpr int BLK = 1024;
__global__ void __launch_bounds__(256) hemp_zero_kernel(int* __restrict__ counts) {
    int i = blockIdx.x * 256 + threadIdx.x;
    if (i < B * T) counts[i] = 0;
}
__global__ void __launch_bounds__(256) hemp_count1_kernel(const int* __restrict__ gid,
                                                          int* __restrict__ counts) {
    int idx = blockIdx.x * 256 + threadIdx.x;
    if (idx < B * N) {
        int b = idx / N;
        atomicAdd(&counts[b * T + gid[idx]], 1);
    }
}
__global__ void __launch_bounds__(BLK) hemp_atomic_kernel(const float* __restrict__ feat,
                                                          const int* __restrict__ gid,
                                                          const int* __restrict__ counts,
                                                          float* __restrict__ out) {
    extern __shared__ float lds_sum[];
    const int tid = threadIdx.x;
    const int b = blockIdx.x >> 8;
    const int c = blockIdx.x & 255;
    float4* ls4 = reinterpret_cast<float4*>(lds_sum);
    for (int t = tid; t < T / 4; t += BLK) ls4[t] = make_float4(0.f, 0.f, 0.f, 0.f);
    __syncthreads();
    const float4* f4 = reinterpret_cast<const float4*>(feat + (size_t)(b * C + c) * N);
    const int4* g4 = reinterpret_cast<const int4*>(gid + (size_t)b * N);
    for (int i = tid; i < N / 4; i += BLK) {
        float4 v = f4[i];
        int4 g = g4[i];
        unsafeAtomicAdd(&lds_sum[g.x], v.x);
        unsafeAtomicAdd(&lds_sum[g.y], v.y);
        unsafeAtomicAdd(&lds_sum[g.z], v.z);
        unsafeAtomicAdd(&lds_sum[g.w], v.w);
    }
    __syncthreads();
    const int4* cnt4 = reinterpret_cast<const int4*>(counts + (size_t)b * T);
    float4* out4 = reinterpret_cast<float4*>(out + (size_t)(b * C + c) * T);
    for (int t = tid; t < T / 4; t += BLK) {
        int4 cn = cnt4[t];
        float4 s = ls4[t];
        float4 r;
        r.x = s.x / fmaxf((float)cn.x, 1.0f);
        r.y = s.y / fmaxf((float)cn.y, 1.0f);
        r.z = s.z / fmaxf((float)cn.z, 1.0f);
        r.w = s.w / fmaxf((float)cn.w, 1.0f);
        out4[t] = r;
    }
}

extern "C" void kernel_launch(void* const* d_in, const int* in_sizes, int n_in,
                              void* d_out, int out_size, void* d_ws, size_t ws_size,
                              hipStream_t stream) {
    const float* feat = (const float*)d_in[0];
    const int* gid = (const int*)d_in[1];
    float* out = (float*)d_out;

    // ws: head[B*T] i32 | mt[B*T*PAD] u16 | of[B*N] u32 | hg[B*MAXH] i32 | hcnt[B] | ocnt[B]
    char* p = (char*)d_ws;
    int* head = (int*)p;            p += (size_t)B * T * 4;
    ushort* mt = (ushort*)p;        p += (size_t)B * T * PAD * 2;
    unsigned* of = (unsigned*)p;    p += (size_t)B * N * 4;
    int* hg = (int*)p;              p += (size_t)B * MAXH * 4;
    int* hcnt = (int*)p;            p += (size_t)B * 4;
    int* ocnt = (int*)p;            p += (size_t)B * 4;
    size_t need = (size_t)(p - (char*)d_ws);

    if (ws_size >= need) {
        hemp_init_kernel<<<2560, 256, 0, stream>>>(head, (unsigned*)mt, hcnt, ocnt);
        hemp_fill_kernel<<<(B * N / 4 + 255) / 256, 256, 0, stream>>>(gid, head, mt, of,
                                                                      hg, hcnt, ocnt);
        const int lds_bytes = LDSU * 2;  // 80896 B -> 2 blocks/CU
        hipFuncSetAttribute(reinterpret_cast<const void*>(hemp_fused_kernel),
                            hipFuncAttributeMaxDynamicSharedMemorySize, lds_bytes);
        hemp_fused_kernel<<<B * C, FTH, lds_bytes, stream>>>(feat, mt, head, of, hg,
                                                             hcnt, ocnt, out);
    } else {
        int* cnts = (int*)d_ws;
        hemp_zero_kernel<<<(B * T + 255) / 256, 256, 0, stream>>>(cnts);
        hemp_count1_kernel<<<(B * N + 255) / 256, 256, 0, stream>>>(gid, cnts);
        const size_t lds_bytes = (size_t)T * sizeof(float);
        hipFuncSetAttribute(reinterpret_cast<const void*>(hemp_atomic_kernel),
                            hipFuncAttributeMaxDynamicSharedMemorySize, (int)lds_bytes);
        hemp_atomic_kernel<<<B * C, BLK, lds_bytes, stream>>>(feat, gid, cnts, out);
    }
}